// Round 8
// baseline (1366.342 us; speedup 1.0000x reference)
//
#include <hip/hip_runtime.h>
#include <hip/hip_fp16.h>

#define EMBED_DIM 64
#define NBMAX 1024          // max buckets
#define RPB 128             // rows per bucket
#define RPB_SHIFT 7
#define CAP 6144            // slot capacity per bucket (+32 sigma), bounds-checked
#define CHUNK 8192          // edges per WG in binning scatter
#define SCAT_T 512
#define EPT (CHUNK / SCAT_T)
#define NBLK 8              // col blocks (col >> 14: 16384 cols = 2MiB fp16 slice)
#define CBLK_SHIFT 14
#define BINS (RPB * NBLK)   // 1024 sort bins: (local_row << 3) | col_block
#define GWG 512             // gather grid (2 WG/CU guaranteed co-resident)
#define GT 512              // gather threads per WG
#define GR 4                // row-slices per gather thread

__device__ __forceinline__ int load_idx(const void* p, int e, bool i64) {
    return i64 ? (int)((const long long*)p)[e] : ((const int*)p)[e];
}

// ---------------------------------------------------------------------------
// Detect index dtype (int64 values < 2^17 -> odd u32 words all zero), zero
// bucket cursors and barrier counters. One WG, every call (ws not re-zeroed
// between graph replays).
// ---------------------------------------------------------------------------
__global__ __launch_bounds__(1024) void detect_zero_kernel(
    const unsigned int* __restrict__ rows_u32, int* __restrict__ base, int nb) {
    const int tid = threadIdx.x;
    if (tid == 0) {
        int nz = 0;
        for (int i = 1; i < 128; i += 2) nz += (rows_u32[i] != 0u);
        base[0] = (nz == 0) ? 1 : 0;
    }
    if (tid < nb) base[4 + tid] = 0;               // gcur
    if (tid < 128) base[4 + NBMAX + tid] = 0;      // barrier counters
}

// ---------------------------------------------------------------------------
// x (f32) -> xh (fp16). |x| small; accumulated output err ~0.04 << 0.3975.
// ---------------------------------------------------------------------------
__global__ __launch_bounds__(256) void xconv_kernel(
    const float* __restrict__ x, ushort* __restrict__ xh, int n8) {
    int i = blockIdx.x * 256 + threadIdx.x;
    if (i >= n8) return;
    float4 a = ((const float4*)x)[i * 2];
    float4 b = ((const float4*)x)[i * 2 + 1];
    ushort h[8];
    h[0] = __half_as_ushort(__float2half_rn(a.x));
    h[1] = __half_as_ushort(__float2half_rn(a.y));
    h[2] = __half_as_ushort(__float2half_rn(a.z));
    h[3] = __half_as_ushort(__float2half_rn(a.w));
    h[4] = __half_as_ushort(__float2half_rn(b.x));
    h[5] = __half_as_ushort(__float2half_rn(b.y));
    h[6] = __half_as_ushort(__float2half_rn(b.z));
    h[7] = __half_as_ushort(__float2half_rn(b.w));
    ((uint4*)xh)[i] = *(const uint4*)h;
}

// ---------------------------------------------------------------------------
// Phase 1: bin edges into slotted bucket array (bucket b owns recs[b*CAP..]).
// ---------------------------------------------------------------------------
__global__ __launch_bounds__(SCAT_T) void bscatter_kernel(
    const void* __restrict__ rows_p, const void* __restrict__ cols_p,
    const float* __restrict__ vals, int* __restrict__ gcur,
    uint2* __restrict__ recs, const int* __restrict__ flag_p, int n_edges) {
    __shared__ int h[NBMAX];
    __shared__ int base[NBMAX];
    const bool i64 = (*flag_p != 0);
    const int tid = threadIdx.x;
    const int c0 = blockIdx.x * CHUNK;
    int rloc[EPT];

    for (int i = tid; i < NBMAX; i += SCAT_T) h[i] = 0;
    __syncthreads();

    #pragma unroll
    for (int k = 0; k < EPT; ++k) {
        int e = c0 + k * SCAT_T + tid;
        int r = (e < n_edges) ? load_idx(rows_p, e, i64) : -1;
        rloc[k] = r;
        if (r >= 0) atomicAdd(&h[r >> RPB_SHIFT], 1);
    }
    __syncthreads();

    for (int i = tid; i < NBMAX; i += SCAT_T) {
        int c = h[i];
        base[i] = c ? (i * CAP + atomicAdd(&gcur[i], c)) : 0;
        h[i] = 0;
    }
    __syncthreads();

    #pragma unroll
    for (int k0 = 0; k0 < EPT; k0 += 4) {
        int cc[4]; float vv[4];
        #pragma unroll
        for (int j = 0; j < 4; ++j) {
            int e = c0 + (k0 + j) * SCAT_T + tid;
            if (rloc[k0 + j] >= 0) {
                cc[j] = load_idx(cols_p, e, i64);
                vv[j] = vals[e];
            }
        }
        #pragma unroll
        for (int j = 0; j < 4; ++j) {
            int r = rloc[k0 + j];
            if (r >= 0) {
                int b = r >> RPB_SHIFT;
                int pos = base[b] + atomicAdd(&h[b], 1);
                if (pos < (b + 1) * CAP)
                    recs[pos] = make_uint2(
                        ((unsigned)(r & (RPB - 1)) << 20) | (unsigned)cc[j],
                        __float_as_uint(vv[j]));
            }
        }
    }
}

// ---------------------------------------------------------------------------
// Phase 2: per-bucket counting sort, key = (local_row, col_block) -> 1024
// bins. Emits srange8[blk*N + row] = {start,end} (block-major for dense
// per-phase reads) and recs2 sorted {col, val}.
// ---------------------------------------------------------------------------
__global__ __launch_bounds__(1024) void bsort_kernel(
    const int* __restrict__ gcur, const uint2* __restrict__ recs,
    uint2* __restrict__ recs2, uint2* __restrict__ srange8, int N) {
    __shared__ int cnt[BINS];
    __shared__ int scn[BINS];
    __shared__ int rbase[BINS];
    const int b = blockIdx.x;
    const int tid = threadIdx.x;
    const int s = b * CAP;
    int n = gcur[b];
    if (n > CAP) n = CAP;

    cnt[tid] = 0;
    __syncthreads();

    for (int i = tid; i < n; i += 1024) {
        unsigned k = recs[s + i].x;
        int bin = (int)((k >> 20) << 3) | (int)((k & 0xFFFFFu) >> CBLK_SHIFT);
        atomicAdd(&cnt[bin], 1);
    }
    __syncthreads();

    scn[tid] = cnt[tid];
    __syncthreads();
    for (int d = 1; d < BINS; d <<= 1) {
        int u = (tid >= d) ? scn[tid - d] : 0;
        __syncthreads();
        scn[tid] += u;
        __syncthreads();
    }
    {
        int excl = scn[tid] - cnt[tid];
        rbase[tid] = excl;
        int row = b * RPB + (tid >> 3);
        int blk = tid & 7;
        if (row < N)
            srange8[(size_t)blk * N + row] =
                make_uint2(s + excl, s + excl + cnt[tid]);
        cnt[tid] = 0;              // reuse as cursor
    }
    __syncthreads();

    for (int i = tid; i < n; i += 1024) {
        uint2 rc = recs[s + i];
        int bin = (int)((rc.x >> 20) << 3) |
                  (int)((rc.x & 0xFFFFFu) >> CBLK_SHIFT);
        int pos = s + rbase[bin] + atomicAdd(&cnt[bin], 1);
        recs2[pos] = make_uint2(rc.x & 0xFFFFFu, rc.y);
    }
}

// ---------------------------------------------------------------------------
// Soft global barrier: monotonic arrivals split over 8 cache lines, bounded
// spin (perf-only; timeout => proceed, never deadlock, never wrong).
// ---------------------------------------------------------------------------
__device__ __forceinline__ void soft_barrier(int* barr, int target) {
    __syncthreads();
    if (threadIdx.x == 0) {
        __hip_atomic_fetch_add(&barr[(blockIdx.x & 7) * 16], 1,
                               __ATOMIC_ACQ_REL, __HIP_MEMORY_SCOPE_AGENT);
        for (int it = 0; it < 4096; ++it) {
            int ssum = 0;
            #pragma unroll
            for (int j = 0; j < 8; ++j)
                ssum += __hip_atomic_load(&barr[j * 16], __ATOMIC_ACQUIRE,
                                          __HIP_MEMORY_SCOPE_AGENT);
            if (ssum >= target) break;
            __builtin_amdgcn_s_sleep(2);
        }
    }
    __syncthreads();
}

// ---------------------------------------------------------------------------
// Phase 3: persistent phase-synced gather. 512 WGs x 512 threads (2 WG/CU
// co-resident); each thread owns GR=4 row-slices (8 lanes/row, lane = 8 dims),
// acc in registers across all 8 col-block phases. Within a phase the whole
// device gathers from one 2MiB x-slice -> per-XCD L2-resident.
// ---------------------------------------------------------------------------
__global__ __launch_bounds__(GT, 4) void gather_phased(
    const uint2* __restrict__ srange8, const uint2* __restrict__ recs2,
    const ushort* __restrict__ xh, float* __restrict__ out, int N,
    int* __restrict__ barr) {
    const int tid = threadIdx.x;
    const int g0 = blockIdx.x * GT + tid;
    const int S = GWG * GT;
    const int nslice = N * 8;
    float acc[GR][8] = {};

    #define ACC8(A, U, V)                                                  \
        {                                                                  \
            float2 f0 = __half22float2(*(const __half2*)&(U).x);           \
            float2 f1 = __half22float2(*(const __half2*)&(U).y);           \
            float2 f2 = __half22float2(*(const __half2*)&(U).z);           \
            float2 f3 = __half22float2(*(const __half2*)&(U).w);           \
            A[0] += (V) * f0.x; A[1] += (V) * f0.y;                        \
            A[2] += (V) * f1.x; A[3] += (V) * f1.y;                        \
            A[4] += (V) * f2.x; A[5] += (V) * f2.y;                        \
            A[6] += (V) * f3.x; A[7] += (V) * f3.y;                        \
        }

    for (int blk = 0; blk < NBLK; ++blk) {
        #pragma unroll
        for (int rr = 0; rr < GR; ++rr) {
            int g = g0 + rr * S;
            if (g < nslice) {
                int row = g >> 3;
                int lane = g & 7;
                uint2 rg = srange8[(size_t)blk * N + row];
                int e = (int)rg.x;
                const int e_end = (int)rg.y;
                for (; e + 4 <= e_end; e += 4) {
                    uint2 r0 = recs2[e],     r1 = recs2[e + 1];
                    uint2 r2 = recs2[e + 2], r3 = recs2[e + 3];
                    uint4 a0 = ((const uint4*)(xh + (size_t)r0.x * EMBED_DIM))[lane];
                    uint4 a1 = ((const uint4*)(xh + (size_t)r1.x * EMBED_DIM))[lane];
                    uint4 a2 = ((const uint4*)(xh + (size_t)r2.x * EMBED_DIM))[lane];
                    uint4 a3 = ((const uint4*)(xh + (size_t)r3.x * EMBED_DIM))[lane];
                    float v0 = __uint_as_float(r0.y), v1 = __uint_as_float(r1.y);
                    float v2 = __uint_as_float(r2.y), v3 = __uint_as_float(r3.y);
                    ACC8(acc[rr], a0, v0); ACC8(acc[rr], a1, v1);
                    ACC8(acc[rr], a2, v2); ACC8(acc[rr], a3, v3);
                }
                for (; e < e_end; ++e) {
                    uint2 r0 = recs2[e];
                    uint4 a0 = ((const uint4*)(xh + (size_t)r0.x * EMBED_DIM))[lane];
                    float v0 = __uint_as_float(r0.y);
                    ACC8(acc[rr], a0, v0);
                }
            }
        }
        if (blk < NBLK - 1) soft_barrier(barr, GWG * (blk + 1));
    }
    #undef ACC8

    #pragma unroll
    for (int rr = 0; rr < GR; ++rr) {
        int g = g0 + rr * S;
        if (g < nslice) {
            int row = g >> 3;
            int lane = g & 7;
            float4* op = (float4*)(out + (size_t)row * EMBED_DIM);
            op[lane * 2]     = make_float4(acc[rr][0], acc[rr][1],
                                           acc[rr][2], acc[rr][3]);
            op[lane * 2 + 1] = make_float4(acc[rr][4], acc[rr][5],
                                           acc[rr][6], acc[rr][7]);
        }
    }
}

// ---------------------------------------------------------------------------
// Fallback: atomic COO (f32) if workspace/shape constraints violated.
// ---------------------------------------------------------------------------
__global__ __launch_bounds__(256) void spmv_coo_kernel(
    const void* __restrict__ rows_p, const void* __restrict__ cols_p,
    const float* __restrict__ vals, const float* __restrict__ x,
    float* __restrict__ out, const int* __restrict__ flag_p, int n_edges) {
    const bool i64 = (*flag_p != 0);
    const int lane16 = threadIdx.x & 15;
    long long t      = (long long)blockIdx.x * blockDim.x + threadIdx.x;
    long long stride = (long long)gridDim.x * blockDim.x;
    long long total  = (long long)n_edges * 16;
    for (; t < total; t += stride) {
        int e = (int)(t >> 4);
        int r = load_idx(rows_p, e, i64);
        int c = load_idx(cols_p, e, i64);
        float v = vals[e];
        float4 xv = ((const float4*)(x + (long long)c * EMBED_DIM))[lane16];
        float* o = out + (long long)r * EMBED_DIM + lane16 * 4;
        unsafeAtomicAdd(o + 0, xv.x * v);
        unsafeAtomicAdd(o + 1, xv.y * v);
        unsafeAtomicAdd(o + 2, xv.z * v);
        unsafeAtomicAdd(o + 3, xv.w * v);
    }
}

extern "C" void kernel_launch(void* const* d_in, const int* in_sizes, int n_in,
                              void* d_out, int out_size, void* d_ws, size_t ws_size,
                              hipStream_t stream) {
    const float* x    = (const float*)d_in[0];
    const void*  rows = d_in[1];
    const void*  cols = d_in[2];
    const float* vals = (const float*)d_in[3];
    float* out = (float*)d_out;
    const int E = in_sizes[1];
    const int N = out_size / EMBED_DIM;
    const int NB = (N + RPB - 1) >> RPB_SHIFT;

    // Workspace layout: flag[4 ints] | gcur[NBMAX ints] | bar[128 ints] |
    // xh[N*64 halves] | srange8[NBLK*N uint2] | recs[NB*CAP u2] | recs2[...]
    int*    base    = (int*)d_ws;
    int*    flag    = base;
    int*    gcur    = base + 4;
    int*    barr    = base + 4 + NBMAX;
    ushort* xh      = (ushort*)(barr + 128);           // 4624 B offset, 16B-aligned
    uint2*  srange8 = (uint2*)(xh + (size_t)N * EMBED_DIM);
    uint2*  recs    = srange8 + (size_t)NBLK * N;
    uint2*  recs2   = recs + (size_t)NB * CAP;
    const size_t needed = (size_t)(4 + NBMAX + 128) * 4
                        + (size_t)N * EMBED_DIM * 2
                        + (size_t)NBLK * N * 8
                        + (size_t)NB * CAP * 8 * 2;

    if (ws_size < needed || NB > NBMAX || N > (1 << 20) ||
        (size_t)NB * CAP < (size_t)E / 2) {
        detect_zero_kernel<<<1, 1024, 0, stream>>>((const unsigned int*)rows,
                                                   base, 0);
        hipMemsetAsync(d_out, 0, (size_t)out_size * sizeof(float), stream);
        spmv_coo_kernel<<<8192, 256, 0, stream>>>(rows, cols, vals, x, out,
                                                  flag, E);
        return;
    }

    detect_zero_kernel<<<1, 1024, 0, stream>>>((const unsigned int*)rows,
                                               base, NB);
    const int n8 = N * EMBED_DIM / 8;
    xconv_kernel<<<(n8 + 255) / 256, 256, 0, stream>>>(x, xh, n8);
    const int grid_c = (E + CHUNK - 1) / CHUNK;
    bscatter_kernel<<<grid_c, SCAT_T, 0, stream>>>(rows, cols, vals, gcur,
                                                   recs, flag, E);
    bsort_kernel<<<NB, 1024, 0, stream>>>(gcur, recs, recs2, srange8, N);
    gather_phased<<<GWG, GT, 0, stream>>>(srange8, recs2, xh, out, N, barr);
}

// Round 9
// 737.392 us; speedup vs baseline: 1.8529x; 1.8529x over previous
//
#include <hip/hip_runtime.h>
#include <hip/hip_fp16.h>

#define EMBED_DIM 64
#define NBMAX 1024          // max buckets
#define RPB 128             // rows per bucket
#define RPB_SHIFT 7
#define CAP 6144            // slot capacity per bucket (+32 sigma), bounds-checked
#define CHUNK 8192          // edges per WG in binning scatter
#define SCAT_T 512
#define EPT (CHUNK / SCAT_T)
#define NBLK 8              // col blocks (col >> 14: 16384 cols = 2MiB fp16 slice)
#define CBLK_SHIFT 14
#define BINS (RPB * NBLK)   // 1024 sort bins: (local_row << 3) | col_block
#define GWG 512             // gather grid (2 WG/CU co-resident)
#define GT 512              // gather threads per WG

typedef float f32x8 __attribute__((ext_vector_type(8)));

__device__ __forceinline__ int load_idx(const void* p, int e, bool i64) {
    return i64 ? (int)((const long long*)p)[e] : ((const int*)p)[e];
}

// ---------------------------------------------------------------------------
// Detect index dtype (int64 values < 2^17 -> odd u32 words all zero), zero
// bucket cursors and barrier counters. One WG, every call.
// ---------------------------------------------------------------------------
__global__ __launch_bounds__(1024) void detect_zero_kernel(
    const unsigned int* __restrict__ rows_u32, int* __restrict__ base, int nb) {
    const int tid = threadIdx.x;
    if (tid == 0) {
        int nz = 0;
        for (int i = 1; i < 128; i += 2) nz += (rows_u32[i] != 0u);
        base[0] = (nz == 0) ? 1 : 0;
    }
    if (tid < nb) base[4 + tid] = 0;               // gcur
    if (tid < 128) base[4 + NBMAX + tid] = 0;      // barrier counters
}

// ---------------------------------------------------------------------------
// x (f32) -> xh (fp16). |x| small; accumulated output err ~0.04 << 0.3975.
// ---------------------------------------------------------------------------
__global__ __launch_bounds__(256) void xconv_kernel(
    const float* __restrict__ x, ushort* __restrict__ xh, int n8) {
    int i = blockIdx.x * 256 + threadIdx.x;
    if (i >= n8) return;
    float4 a = ((const float4*)x)[i * 2];
    float4 b = ((const float4*)x)[i * 2 + 1];
    ushort h[8];
    h[0] = __half_as_ushort(__float2half_rn(a.x));
    h[1] = __half_as_ushort(__float2half_rn(a.y));
    h[2] = __half_as_ushort(__float2half_rn(a.z));
    h[3] = __half_as_ushort(__float2half_rn(a.w));
    h[4] = __half_as_ushort(__float2half_rn(b.x));
    h[5] = __half_as_ushort(__float2half_rn(b.y));
    h[6] = __half_as_ushort(__float2half_rn(b.z));
    h[7] = __half_as_ushort(__float2half_rn(b.w));
    ((uint4*)xh)[i] = *(const uint4*)h;
}

// ---------------------------------------------------------------------------
// Phase 1: bin edges into slotted bucket array (bucket b owns recs[b*CAP..]).
// ---------------------------------------------------------------------------
__global__ __launch_bounds__(SCAT_T) void bscatter_kernel(
    const void* __restrict__ rows_p, const void* __restrict__ cols_p,
    const float* __restrict__ vals, int* __restrict__ gcur,
    uint2* __restrict__ recs, const int* __restrict__ flag_p, int n_edges) {
    __shared__ int h[NBMAX];
    __shared__ int base[NBMAX];
    const bool i64 = (*flag_p != 0);
    const int tid = threadIdx.x;
    const int c0 = blockIdx.x * CHUNK;
    int rloc[EPT];

    for (int i = tid; i < NBMAX; i += SCAT_T) h[i] = 0;
    __syncthreads();

    #pragma unroll
    for (int k = 0; k < EPT; ++k) {
        int e = c0 + k * SCAT_T + tid;
        int r = (e < n_edges) ? load_idx(rows_p, e, i64) : -1;
        rloc[k] = r;
        if (r >= 0) atomicAdd(&h[r >> RPB_SHIFT], 1);
    }
    __syncthreads();

    for (int i = tid; i < NBMAX; i += SCAT_T) {
        int c = h[i];
        base[i] = c ? (i * CAP + atomicAdd(&gcur[i], c)) : 0;
        h[i] = 0;
    }
    __syncthreads();

    #pragma unroll
    for (int k0 = 0; k0 < EPT; k0 += 4) {
        int cc[4]; float vv[4];
        #pragma unroll
        for (int j = 0; j < 4; ++j) {
            int e = c0 + (k0 + j) * SCAT_T + tid;
            if (rloc[k0 + j] >= 0) {
                cc[j] = load_idx(cols_p, e, i64);
                vv[j] = vals[e];
            }
        }
        #pragma unroll
        for (int j = 0; j < 4; ++j) {
            int r = rloc[k0 + j];
            if (r >= 0) {
                int b = r >> RPB_SHIFT;
                int pos = base[b] + atomicAdd(&h[b], 1);
                if (pos < (b + 1) * CAP)
                    recs[pos] = make_uint2(
                        ((unsigned)(r & (RPB - 1)) << 20) | (unsigned)cc[j],
                        __float_as_uint(vv[j]));
            }
        }
    }
}

// ---------------------------------------------------------------------------
// Phase 2: per-bucket counting sort, key = (local_row, col_block) -> 1024
// bins. Emits srange8[blk*N + row] = {start,end} and recs2 sorted {col,val}.
// ---------------------------------------------------------------------------
__global__ __launch_bounds__(1024) void bsort_kernel(
    const int* __restrict__ gcur, const uint2* __restrict__ recs,
    uint2* __restrict__ recs2, uint2* __restrict__ srange8, int N) {
    __shared__ int cnt[BINS];
    __shared__ int scn[BINS];
    __shared__ int rbase[BINS];
    const int b = blockIdx.x;
    const int tid = threadIdx.x;
    const int s = b * CAP;
    int n = gcur[b];
    if (n > CAP) n = CAP;

    cnt[tid] = 0;
    __syncthreads();

    for (int i = tid; i < n; i += 1024) {
        unsigned k = recs[s + i].x;
        int bin = (int)((k >> 20) << 3) | (int)((k & 0xFFFFFu) >> CBLK_SHIFT);
        atomicAdd(&cnt[bin], 1);
    }
    __syncthreads();

    scn[tid] = cnt[tid];
    __syncthreads();
    for (int d = 1; d < BINS; d <<= 1) {
        int u = (tid >= d) ? scn[tid - d] : 0;
        __syncthreads();
        scn[tid] += u;
        __syncthreads();
    }
    {
        int excl = scn[tid] - cnt[tid];
        rbase[tid] = excl;
        int row = b * RPB + (tid >> 3);
        int blk = tid & 7;
        if (row < N)
            srange8[(size_t)blk * N + row] =
                make_uint2(s + excl, s + excl + cnt[tid]);
        cnt[tid] = 0;              // reuse as cursor
    }
    __syncthreads();

    for (int i = tid; i < n; i += 1024) {
        uint2 rc = recs[s + i];
        int bin = (int)((rc.x >> 20) << 3) |
                  (int)((rc.x & 0xFFFFFu) >> CBLK_SHIFT);
        int pos = s + rbase[bin] + atomicAdd(&cnt[bin], 1);
        recs2[pos] = make_uint2(rc.x & 0xFFFFFu, rc.y);
    }
}

// ---------------------------------------------------------------------------
// Soft global barrier: monotonic arrivals split over 8 cache lines, bounded
// spin (perf-only; timeout => proceed, never deadlock, never wrong).
// ---------------------------------------------------------------------------
__device__ __forceinline__ void soft_barrier(int* barr, int target) {
    __syncthreads();
    if (threadIdx.x == 0) {
        __hip_atomic_fetch_add(&barr[(blockIdx.x & 7) * 16], 1,
                               __ATOMIC_ACQ_REL, __HIP_MEMORY_SCOPE_AGENT);
        for (int it = 0; it < 4096; ++it) {
            int ssum = 0;
            #pragma unroll
            for (int j = 0; j < 8; ++j)
                ssum += __hip_atomic_load(&barr[j * 16], __ATOMIC_ACQUIRE,
                                          __HIP_MEMORY_SCOPE_AGENT);
            if (ssum >= target) break;
            __builtin_amdgcn_s_sleep(2);
        }
    }
    __syncthreads();
}

// ---------------------------------------------------------------------------
// Gather one (row, lane) slice for one col-block. A is a NAMED ext-vector
// accumulator passed by reference -- every element index below is a
// compile-time constant, so A stays in VGPRs (round-8's acc[rr][j] runtime
// indexing sent the accumulator to scratch: 1.8GB of spill writes).
// ---------------------------------------------------------------------------
__device__ __forceinline__ void gather_slice(
    int g, int nslice, int blk, int N, const uint2* __restrict__ srange8,
    const uint2* __restrict__ recs2, const ushort* __restrict__ xh, f32x8& A) {
    if (g >= nslice) return;
    const int row = g >> 3;
    const int lane = g & 7;
    uint2 rg = srange8[(size_t)blk * N + row];
    int e = (int)rg.x;
    const int e_end = (int)rg.y;

    #define ACC8(U, V)                                                     \
        {                                                                  \
            float2 f0 = __half22float2(*(const __half2*)&(U).x);           \
            float2 f1 = __half22float2(*(const __half2*)&(U).y);           \
            float2 f2 = __half22float2(*(const __half2*)&(U).z);           \
            float2 f3 = __half22float2(*(const __half2*)&(U).w);           \
            A[0] += (V) * f0.x; A[1] += (V) * f0.y;                        \
            A[2] += (V) * f1.x; A[3] += (V) * f1.y;                        \
            A[4] += (V) * f2.x; A[5] += (V) * f2.y;                        \
            A[6] += (V) * f3.x; A[7] += (V) * f3.y;                        \
        }

    for (; e + 4 <= e_end; e += 4) {
        uint2 r0 = recs2[e],     r1 = recs2[e + 1];
        uint2 r2 = recs2[e + 2], r3 = recs2[e + 3];
        uint4 a0 = ((const uint4*)(xh + (size_t)r0.x * EMBED_DIM))[lane];
        uint4 a1 = ((const uint4*)(xh + (size_t)r1.x * EMBED_DIM))[lane];
        uint4 a2 = ((const uint4*)(xh + (size_t)r2.x * EMBED_DIM))[lane];
        uint4 a3 = ((const uint4*)(xh + (size_t)r3.x * EMBED_DIM))[lane];
        float v0 = __uint_as_float(r0.y), v1 = __uint_as_float(r1.y);
        float v2 = __uint_as_float(r2.y), v3 = __uint_as_float(r3.y);
        ACC8(a0, v0); ACC8(a1, v1); ACC8(a2, v2); ACC8(a3, v3);
    }
    for (; e < e_end; ++e) {
        uint2 r0 = recs2[e];
        uint4 a0 = ((const uint4*)(xh + (size_t)r0.x * EMBED_DIM))[lane];
        float v0 = __uint_as_float(r0.y);
        ACC8(a0, v0);
    }
    #undef ACC8
}

__device__ __forceinline__ void store_slice(
    int g, int nslice, float* __restrict__ out, const f32x8& A) {
    if (g >= nslice) return;
    const int row = g >> 3;
    const int lane = g & 7;
    float4* op = (float4*)(out + (size_t)row * EMBED_DIM);
    op[lane * 2]     = make_float4(A[0], A[1], A[2], A[3]);
    op[lane * 2 + 1] = make_float4(A[4], A[5], A[6], A[7]);
}

// ---------------------------------------------------------------------------
// Phase 3: persistent phase-synced gather. 512 WGs x 512 threads; each thread
// owns 4 row-slices (named accumulators a0..a3, all VGPR-resident); sweeps
// col-blocks 0..7 with a soft global barrier so the whole device reads the
// same 2MiB x-slice (per-XCD L2-resident) during each phase.
// ---------------------------------------------------------------------------
__global__ __launch_bounds__(GT, 4) void gather_phased(
    const uint2* __restrict__ srange8, const uint2* __restrict__ recs2,
    const ushort* __restrict__ xh, float* __restrict__ out, int N,
    int* __restrict__ barr) {
    const int g0 = blockIdx.x * GT + threadIdx.x;
    const int S = GWG * GT;
    const int nslice = N * 8;
    f32x8 a0 = {}, a1 = {}, a2 = {}, a3 = {};

    for (int blk = 0; blk < NBLK; ++blk) {
        gather_slice(g0 + 0 * S, nslice, blk, N, srange8, recs2, xh, a0);
        gather_slice(g0 + 1 * S, nslice, blk, N, srange8, recs2, xh, a1);
        gather_slice(g0 + 2 * S, nslice, blk, N, srange8, recs2, xh, a2);
        gather_slice(g0 + 3 * S, nslice, blk, N, srange8, recs2, xh, a3);
        if (blk < NBLK - 1) soft_barrier(barr, GWG * (blk + 1));
    }

    store_slice(g0 + 0 * S, nslice, out, a0);
    store_slice(g0 + 1 * S, nslice, out, a1);
    store_slice(g0 + 2 * S, nslice, out, a2);
    store_slice(g0 + 3 * S, nslice, out, a3);
}

// ---------------------------------------------------------------------------
// Fallback: atomic COO (f32) if workspace/shape constraints violated.
// ---------------------------------------------------------------------------
__global__ __launch_bounds__(256) void spmv_coo_kernel(
    const void* __restrict__ rows_p, const void* __restrict__ cols_p,
    const float* __restrict__ vals, const float* __restrict__ x,
    float* __restrict__ out, const int* __restrict__ flag_p, int n_edges) {
    const bool i64 = (*flag_p != 0);
    const int lane16 = threadIdx.x & 15;
    long long t      = (long long)blockIdx.x * blockDim.x + threadIdx.x;
    long long stride = (long long)gridDim.x * blockDim.x;
    long long total  = (long long)n_edges * 16;
    for (; t < total; t += stride) {
        int e = (int)(t >> 4);
        int r = load_idx(rows_p, e, i64);
        int c = load_idx(cols_p, e, i64);
        float v = vals[e];
        float4 xv = ((const float4*)(x + (long long)c * EMBED_DIM))[lane16];
        float* o = out + (long long)r * EMBED_DIM + lane16 * 4;
        unsafeAtomicAdd(o + 0, xv.x * v);
        unsafeAtomicAdd(o + 1, xv.y * v);
        unsafeAtomicAdd(o + 2, xv.z * v);
        unsafeAtomicAdd(o + 3, xv.w * v);
    }
}

extern "C" void kernel_launch(void* const* d_in, const int* in_sizes, int n_in,
                              void* d_out, int out_size, void* d_ws, size_t ws_size,
                              hipStream_t stream) {
    const float* x    = (const float*)d_in[0];
    const void*  rows = d_in[1];
    const void*  cols = d_in[2];
    const float* vals = (const float*)d_in[3];
    float* out = (float*)d_out;
    const int E = in_sizes[1];
    const int N = out_size / EMBED_DIM;
    const int NB = (N + RPB - 1) >> RPB_SHIFT;

    // Workspace layout: flag[4 ints] | gcur[NBMAX ints] | bar[128 ints] |
    // xh[N*64 halves] | srange8[NBLK*N uint2] | recs[NB*CAP u2] | recs2[...]
    int*    base    = (int*)d_ws;
    int*    flag    = base;
    int*    gcur    = base + 4;
    int*    barr    = base + 4 + NBMAX;
    ushort* xh      = (ushort*)(barr + 128);           // 4624 B offset, 16B-aligned
    uint2*  srange8 = (uint2*)(xh + (size_t)N * EMBED_DIM);
    uint2*  recs    = srange8 + (size_t)NBLK * N;
    uint2*  recs2   = recs + (size_t)NB * CAP;
    const size_t needed = (size_t)(4 + NBMAX + 128) * 4
                        + (size_t)N * EMBED_DIM * 2
                        + (size_t)NBLK * N * 8
                        + (size_t)NB * CAP * 8 * 2;

    if (ws_size < needed || NB > NBMAX || N > (1 << 20) ||
        (size_t)NB * CAP < (size_t)E / 2) {
        detect_zero_kernel<<<1, 1024, 0, stream>>>((const unsigned int*)rows,
                                                   base, 0);
        hipMemsetAsync(d_out, 0, (size_t)out_size * sizeof(float), stream);
        spmv_coo_kernel<<<8192, 256, 0, stream>>>(rows, cols, vals, x, out,
                                                  flag, E);
        return;
    }

    detect_zero_kernel<<<1, 1024, 0, stream>>>((const unsigned int*)rows,
                                               base, NB);
    const int n8 = N * EMBED_DIM / 8;
    xconv_kernel<<<(n8 + 255) / 256, 256, 0, stream>>>(x, xh, n8);
    const int grid_c = (E + CHUNK - 1) / CHUNK;
    bscatter_kernel<<<grid_c, SCAT_T, 0, stream>>>(rows, cols, vals, gcur,
                                                   recs, flag, E);
    bsort_kernel<<<NB, 1024, 0, stream>>>(gcur, recs, recs2, srange8, N);
    gather_phased<<<GWG, GT, 0, stream>>>(srange8, recs2, xh, out, N, barr);
}

// Round 11
// 280.987 us; speedup vs baseline: 4.8627x; 2.6243x over previous
//
#include <hip/hip_runtime.h>
#include <hip/hip_fp16.h>

#define EMBED_DIM 64
#define NBMAX 1024          // max row buckets
#define RPB 128             // rows per bucket
#define RPB_SHIFT 7
#define CAP 6144            // slots per bucket (+32 sigma vs mean 4092), guarded
#define CHUNK 8192          // edges per WG in binning scatter
#define SCAT_T 512
#define EPT (CHUNK / SCAT_T)
#define DBLK 4              // dim blocks: 16 dims x fp16 x 100K rows = 3.2MB
#define DPB 16              //   -> fits per-XCD 4MiB L2 during each gather pass

typedef float f32x8 __attribute__((ext_vector_type(8)));
typedef float f32x4 __attribute__((ext_vector_type(4)));

__device__ __forceinline__ int load_idx(const void* p, int e, bool i64) {
    return i64 ? (int)((const long long*)p)[e] : ((const int*)p)[e];
}

__device__ __forceinline__ float h2f(ushort u) {
    __half_raw hr; hr.x = u;
    return __half2float(__half(hr));
}

// ---------------------------------------------------------------------------
// Detect index dtype (int64 values < 2^17 -> odd u32 words all zero) and zero
// per-bucket cursors. One WG, every call (ws is not re-zeroed between replays).
// ---------------------------------------------------------------------------
__global__ __launch_bounds__(1024) void detect_zero_kernel(
    const unsigned int* __restrict__ rows_u32, int* __restrict__ base, int nb) {
    const int tid = threadIdx.x;
    if (tid == 0) {
        int nz = 0;
        for (int i = 1; i < 128; i += 2) nz += (rows_u32[i] != 0u);
        base[0] = (nz == 0) ? 1 : 0;
    }
    if (tid < nb) base[4 + tid] = 0;               // gcur
}

// ---------------------------------------------------------------------------
// x (f32, row-major N x 64) -> xq (fp16, dim-block-major: 4 blocks of N x 16).
// Thread t: row r = t>>3, chunk k = t&7 (dims [8k, 8k+8)) -> block k>>1.
// Reads fully coalesced; |x| small so fp16 keeps output err ~0.05 << 0.3975.
// ---------------------------------------------------------------------------
__global__ __launch_bounds__(256) void xconv_kernel(
    const float* __restrict__ x, ushort* __restrict__ xq, int N) {
    int t = blockIdx.x * 256 + threadIdx.x;
    if (t >= N * 8) return;
    const int r = t >> 3, k = t & 7;
    float4 a = ((const float4*)x)[t * 2];
    float4 b = ((const float4*)x)[t * 2 + 1];
    ushort h[8];
    h[0] = __half_as_ushort(__float2half_rn(a.x));
    h[1] = __half_as_ushort(__float2half_rn(a.y));
    h[2] = __half_as_ushort(__float2half_rn(a.z));
    h[3] = __half_as_ushort(__float2half_rn(a.w));
    h[4] = __half_as_ushort(__float2half_rn(b.x));
    h[5] = __half_as_ushort(__float2half_rn(b.y));
    h[6] = __half_as_ushort(__float2half_rn(b.z));
    h[7] = __half_as_ushort(__float2half_rn(b.w));
    ushort* dst = xq + (size_t)(k >> 1) * N * DPB + (size_t)r * DPB + (k & 1) * 8;
    *(uint4*)dst = *(const uint4*)h;
}

// ---------------------------------------------------------------------------
// Phase 1: bin edges into slotted bucket array (bucket b owns recs[b*CAP..]).
// Per-WG: LDS histogram -> one reservation per touched bucket -> scatter
// {local_row<<20|col, val_f32} into private contiguous runs (~84B).
// ---------------------------------------------------------------------------
__global__ __launch_bounds__(SCAT_T) void bscatter_kernel(
    const void* __restrict__ rows_p, const void* __restrict__ cols_p,
    const float* __restrict__ vals, int* __restrict__ gcur,
    uint2* __restrict__ recs, const int* __restrict__ flag_p, int n_edges) {
    __shared__ int h[NBMAX];
    __shared__ int base[NBMAX];
    const bool i64 = (*flag_p != 0);
    const int tid = threadIdx.x;
    const int c0 = blockIdx.x * CHUNK;
    int rloc[EPT];

    for (int i = tid; i < NBMAX; i += SCAT_T) h[i] = 0;
    __syncthreads();

    #pragma unroll
    for (int k = 0; k < EPT; ++k) {
        int e = c0 + k * SCAT_T + tid;
        int r = (e < n_edges) ? load_idx(rows_p, e, i64) : -1;
        rloc[k] = r;
        if (r >= 0) atomicAdd(&h[r >> RPB_SHIFT], 1);
    }
    __syncthreads();

    for (int i = tid; i < NBMAX; i += SCAT_T) {
        int c = h[i];
        base[i] = c ? (i * CAP + atomicAdd(&gcur[i], c)) : 0;
        h[i] = 0;                  // reuse as within-WG cursor
    }
    __syncthreads();

    #pragma unroll
    for (int k0 = 0; k0 < EPT; k0 += 4) {
        int cc[4]; float vv[4];
        #pragma unroll
        for (int j = 0; j < 4; ++j) {
            int e = c0 + (k0 + j) * SCAT_T + tid;
            if (rloc[k0 + j] >= 0) {
                cc[j] = load_idx(cols_p, e, i64);
                vv[j] = vals[e];
            }
        }
        #pragma unroll
        for (int j = 0; j < 4; ++j) {
            int r = rloc[k0 + j];
            if (r >= 0) {
                int b = r >> RPB_SHIFT;
                int pos = base[b] + atomicAdd(&h[b], 1);
                if (pos < (b + 1) * CAP)   // overflow guard (memory safety)
                    recs[pos] = make_uint2(
                        ((unsigned)(r & (RPB - 1)) << 20) | (unsigned)cc[j],
                        __float_as_uint(vv[j]));
            }
        }
    }
}

// ---------------------------------------------------------------------------
// Phase 2: per-bucket counting sort (128 row bins) into row-contiguous order.
// Emits split arrays rc[pos]=col (u32), rv[pos]=val (fp16) -- 19.2MB instead
// of 25.6MB, since the gather passes re-read them DBLK times -- plus absolute
// per-row ranges srange[row] = {start, end}.
// ---------------------------------------------------------------------------
__global__ __launch_bounds__(256) void bsort_kernel(
    const int* __restrict__ gcur, const uint2* __restrict__ recs,
    unsigned* __restrict__ rc, ushort* __restrict__ rv,
    uint2* __restrict__ srange, int N) {
    __shared__ int cnt[RPB];
    __shared__ int scn[RPB];
    __shared__ int rbase[RPB];
    const int b = blockIdx.x;
    const int tid = threadIdx.x;
    const int s = b * CAP;
    int n = gcur[b];
    if (n > CAP) n = CAP;

    if (tid < RPB) cnt[tid] = 0;
    __syncthreads();

    for (int i = tid; i < n; i += 256)
        atomicAdd(&cnt[recs[s + i].x >> 20], 1);
    __syncthreads();

    if (tid < RPB) scn[tid] = cnt[tid];
    __syncthreads();
    for (int d = 1; d < RPB; d <<= 1) {
        int u = (tid < RPB && tid >= d) ? scn[tid - d] : 0;
        __syncthreads();
        if (tid < RPB) scn[tid] += u;
        __syncthreads();
    }
    if (tid < RPB) {
        int excl = scn[tid] - cnt[tid];
        rbase[tid] = excl;
        int row = b * RPB + tid;
        if (row < N) srange[row] = make_uint2(s + excl, s + excl + cnt[tid]);
        cnt[tid] = 0;              // reuse as cursor
    }
    __syncthreads();

    for (int i = tid; i < n; i += 256) {
        uint2 e = recs[s + i];
        int lr = e.x >> 20;
        int pos = s + rbase[lr] + atomicAdd(&cnt[lr], 1);
        rc[pos] = e.x & 0xFFFFFu;
        rv[pos] = __half_as_ushort(__float2half_rn(__uint_as_float(e.y)));
    }
}

// ---------------------------------------------------------------------------
// Phase 3 (x DBLK sequential launches): gather one 16-dim block. The x
// sub-table for this block is 3.2MB -> resident in every XCD's 4MiB L2 while
// this kernel runs; kernel boundaries act as free device-wide phase barriers
// (no in-kernel sync -- round 8/9's soft-barrier approach is dead).
// Thread t: row = t>>1, half = t&1 -> one uint4 (8 fp16 dims) per edge.
// acc is a single named f32x8 (VGPR-resident; rule-#20 safe). out stores are
// nontemporal via clang ext-vector f32x4 (builtin rejects HIP float4 class):
// no L2 pollution; each kernel writes whole distinct 64B lines per row.
// ---------------------------------------------------------------------------
__global__ __launch_bounds__(256) void gather_dim_kernel(
    const uint2* __restrict__ srange, const unsigned* __restrict__ rc,
    const ushort* __restrict__ rv, const ushort* __restrict__ xqb,
    float* __restrict__ out, int N, int dbase) {
    int t = blockIdx.x * 256 + threadIdx.x;
    int row = t >> 1;
    if (row >= N) return;
    const int half = t & 1;

    uint2 rg = srange[row];
    int e = (int)rg.x;
    const int e_end = (int)rg.y;
    const ushort* xb = xqb + half * 8;
    f32x8 A = {};

    #define ACCD(U, V)                                                     \
        {                                                                  \
            float2 f0 = __half22float2(*(const __half2*)&(U).x);           \
            float2 f1 = __half22float2(*(const __half2*)&(U).y);           \
            float2 f2 = __half22float2(*(const __half2*)&(U).z);           \
            float2 f3 = __half22float2(*(const __half2*)&(U).w);           \
            A[0] += (V) * f0.x; A[1] += (V) * f0.y;                        \
            A[2] += (V) * f1.x; A[3] += (V) * f1.y;                        \
            A[4] += (V) * f2.x; A[5] += (V) * f2.y;                        \
            A[6] += (V) * f3.x; A[7] += (V) * f3.y;                        \
        }

    for (; e + 4 <= e_end; e += 4) {
        unsigned c0 = rc[e],     c1 = rc[e + 1];
        unsigned c2 = rc[e + 2], c3 = rc[e + 3];
        ushort u0 = rv[e],     u1 = rv[e + 1];
        ushort u2 = rv[e + 2], u3 = rv[e + 3];
        uint4 a0 = *(const uint4*)(xb + (size_t)c0 * DPB);
        uint4 a1 = *(const uint4*)(xb + (size_t)c1 * DPB);
        uint4 a2 = *(const uint4*)(xb + (size_t)c2 * DPB);
        uint4 a3 = *(const uint4*)(xb + (size_t)c3 * DPB);
        float v0 = h2f(u0), v1 = h2f(u1), v2 = h2f(u2), v3 = h2f(u3);
        ACCD(a0, v0); ACCD(a1, v1); ACCD(a2, v2); ACCD(a3, v3);
    }
    for (; e < e_end; ++e) {
        unsigned c0 = rc[e];
        uint4 a0 = *(const uint4*)(xb + (size_t)c0 * DPB);
        ACCD(a0, h2f(rv[e]));
    }
    #undef ACCD

    f32x4 o0 = {A[0], A[1], A[2], A[3]};
    f32x4 o1 = {A[4], A[5], A[6], A[7]};
    f32x4* op = (f32x4*)(out + (size_t)row * EMBED_DIM + dbase) + half * 2;
    __builtin_nontemporal_store(o0, op);
    __builtin_nontemporal_store(o1, op + 1);
}

// ---------------------------------------------------------------------------
// Fallback: atomic COO (f32) if workspace/shape constraints violated.
// ---------------------------------------------------------------------------
__global__ __launch_bounds__(256) void spmv_coo_kernel(
    const void* __restrict__ rows_p, const void* __restrict__ cols_p,
    const float* __restrict__ vals, const float* __restrict__ x,
    float* __restrict__ out, const int* __restrict__ flag_p, int n_edges) {
    const bool i64 = (*flag_p != 0);
    const int lane16 = threadIdx.x & 15;
    long long t      = (long long)blockIdx.x * blockDim.x + threadIdx.x;
    long long stride = (long long)gridDim.x * blockDim.x;
    long long total  = (long long)n_edges * 16;
    for (; t < total; t += stride) {
        int e = (int)(t >> 4);
        int r = load_idx(rows_p, e, i64);
        int c = load_idx(cols_p, e, i64);
        float v = vals[e];
        float4 xv = ((const float4*)(x + (long long)c * EMBED_DIM))[lane16];
        float* o = out + (long long)r * EMBED_DIM + lane16 * 4;
        unsafeAtomicAdd(o + 0, xv.x * v);
        unsafeAtomicAdd(o + 1, xv.y * v);
        unsafeAtomicAdd(o + 2, xv.z * v);
        unsafeAtomicAdd(o + 3, xv.w * v);
    }
}

extern "C" void kernel_launch(void* const* d_in, const int* in_sizes, int n_in,
                              void* d_out, int out_size, void* d_ws, size_t ws_size,
                              hipStream_t stream) {
    const float* x    = (const float*)d_in[0];
    const void*  rows = d_in[1];
    const void*  cols = d_in[2];
    const float* vals = (const float*)d_in[3];
    float* out = (float*)d_out;
    const int E = in_sizes[1];
    const int N = out_size / EMBED_DIM;
    const int NB = (N + RPB - 1) >> RPB_SHIFT;

    // Workspace layout: flag[4 ints] | gcur[NBMAX ints] | xq[DBLK*N*DPB ushort]
    // | srange[N uint2] | recs[NB*CAP uint2] | rc[NB*CAP u32] | rv[NB*CAP u16]
    int*      base   = (int*)d_ws;
    int*      flag   = base;
    int*      gcur   = base + 4;
    ushort*   xq     = (ushort*)(base + 4 + NBMAX);     // offset 4112B, 16B-aligned
    uint2*    srange = (uint2*)(xq + (size_t)DBLK * N * DPB);
    uint2*    recs   = srange + N;
    unsigned* rc     = (unsigned*)(recs + (size_t)NB * CAP);
    ushort*   rv     = (ushort*)(rc + (size_t)NB * CAP);
    const size_t needed = (size_t)(4 + NBMAX) * 4
                        + (size_t)DBLK * N * DPB * 2
                        + (size_t)N * 8
                        + (size_t)NB * CAP * (8 + 4 + 2);

    if (ws_size < needed || NB > NBMAX || N > (1 << 20) ||
        (size_t)NB * CAP < (size_t)E / 2) {
        detect_zero_kernel<<<1, 1024, 0, stream>>>((const unsigned int*)rows,
                                                   base, 0);
        (void)hipMemsetAsync(d_out, 0, (size_t)out_size * sizeof(float), stream);
        spmv_coo_kernel<<<8192, 256, 0, stream>>>(rows, cols, vals, x, out,
                                                  flag, E);
        return;
    }

    detect_zero_kernel<<<1, 1024, 0, stream>>>((const unsigned int*)rows,
                                               base, NB);
    xconv_kernel<<<(N * 8 + 255) / 256, 256, 0, stream>>>(x, xq, N);
    const int grid_c = (E + CHUNK - 1) / CHUNK;
    bscatter_kernel<<<grid_c, SCAT_T, 0, stream>>>(rows, cols, vals, gcur,
                                                   recs, flag, E);
    bsort_kernel<<<NB, 256, 0, stream>>>(gcur, recs, rc, rv, srange, N);
    const int grid_g = (N * 2 + 255) / 256;
    for (int b = 0; b < DBLK; ++b)
        gather_dim_kernel<<<grid_g, 256, 0, stream>>>(
            srange, rc, rv, xq + (size_t)b * N * DPB, out, N, b * DPB);
}

// Round 12
// 237.940 us; speedup vs baseline: 5.7424x; 1.1809x over previous
//
#include <hip/hip_runtime.h>
#include <hip/hip_fp16.h>

#define EMBED_DIM 64
#define NBMAX 1024          // max row buckets
#define RPB 128             // rows per bucket
#define RPB_SHIFT 7
#define CAP 6144            // slots per bucket (+32 sigma vs mean 4092), guarded
#define CHUNK 4096          // edges per WG: 782 WGs (~3/CU) for latency hiding;
                            // runs ~5.2 recs -> ~2 lines/run, ~same write amp
#define SCAT_T 512
#define EPT (CHUNK / SCAT_T)
#define DBLK 4              // dim blocks: 16 dims x fp16 x 100K rows = 3.2MB/XCD-L2
#define DPB 16

typedef float f32x8 __attribute__((ext_vector_type(8)));
typedef float f32x4 __attribute__((ext_vector_type(4)));

__device__ __forceinline__ int load_idx(const void* p, int e, bool i64) {
    return i64 ? (int)((const long long*)p)[e] : ((const int*)p)[e];
}

__device__ __forceinline__ float h2f(ushort u) {
    __half_raw hr; hr.x = u;
    return __half2float(__half(hr));
}

// ---------------------------------------------------------------------------
// Detect index dtype (int64 values < 2^17 -> odd u32 words all zero) and zero
// per-bucket cursors. One WG, every call.
// ---------------------------------------------------------------------------
__global__ __launch_bounds__(1024) void detect_zero_kernel(
    const unsigned int* __restrict__ rows_u32, int* __restrict__ base, int nb) {
    const int tid = threadIdx.x;
    if (tid == 0) {
        int nz = 0;
        for (int i = 1; i < 128; i += 2) nz += (rows_u32[i] != 0u);
        base[0] = (nz == 0) ? 1 : 0;
    }
    if (tid < nb) base[4 + tid] = 0;               // gcur
}

// ---------------------------------------------------------------------------
// x (f32, row-major N x 64) -> xq (fp16, dim-block-major: 4 blocks of N x 16).
// ---------------------------------------------------------------------------
__global__ __launch_bounds__(256) void xconv_kernel(
    const float* __restrict__ x, ushort* __restrict__ xq, int N) {
    int t = blockIdx.x * 256 + threadIdx.x;
    if (t >= N * 8) return;
    const int r = t >> 3, k = t & 7;
    float4 a = ((const float4*)x)[t * 2];
    float4 b = ((const float4*)x)[t * 2 + 1];
    ushort h[8];
    h[0] = __half_as_ushort(__float2half_rn(a.x));
    h[1] = __half_as_ushort(__float2half_rn(a.y));
    h[2] = __half_as_ushort(__float2half_rn(a.z));
    h[3] = __half_as_ushort(__float2half_rn(a.w));
    h[4] = __half_as_ushort(__float2half_rn(b.x));
    h[5] = __half_as_ushort(__float2half_rn(b.y));
    h[6] = __half_as_ushort(__float2half_rn(b.z));
    h[7] = __half_as_ushort(__float2half_rn(b.w));
    ushort* dst = xq + (size_t)(k >> 1) * N * DPB + (size_t)r * DPB + (k & 1) * 8;
    *(uint4*)dst = *(const uint4*)h;
}

// ---------------------------------------------------------------------------
// Phase 1: bin edges into slotted bucket array (bucket b owns recs[b*CAP..]).
// CHUNK=4096 -> 782 WGs (~3/CU) to hide the load->LDS-atomic->store chains.
// ---------------------------------------------------------------------------
__global__ __launch_bounds__(SCAT_T) void bscatter_kernel(
    const void* __restrict__ rows_p, const void* __restrict__ cols_p,
    const float* __restrict__ vals, int* __restrict__ gcur,
    uint2* __restrict__ recs, const int* __restrict__ flag_p, int n_edges) {
    __shared__ int h[NBMAX];
    __shared__ int base[NBMAX];
    const bool i64 = (*flag_p != 0);
    const int tid = threadIdx.x;
    const int c0 = blockIdx.x * CHUNK;
    int rloc[EPT];

    for (int i = tid; i < NBMAX; i += SCAT_T) h[i] = 0;
    __syncthreads();

    #pragma unroll
    for (int k = 0; k < EPT; ++k) {
        int e = c0 + k * SCAT_T + tid;
        int r = (e < n_edges) ? load_idx(rows_p, e, i64) : -1;
        rloc[k] = r;
        if (r >= 0) atomicAdd(&h[r >> RPB_SHIFT], 1);
    }
    __syncthreads();

    for (int i = tid; i < NBMAX; i += SCAT_T) {
        int c = h[i];
        base[i] = c ? (i * CAP + atomicAdd(&gcur[i], c)) : 0;
        h[i] = 0;                  // reuse as within-WG cursor
    }
    __syncthreads();

    #pragma unroll
    for (int k0 = 0; k0 < EPT; k0 += 4) {
        int cc[4]; float vv[4];
        #pragma unroll
        for (int j = 0; j < 4; ++j) {
            int e = c0 + (k0 + j) * SCAT_T + tid;
            if (rloc[k0 + j] >= 0) {
                cc[j] = load_idx(cols_p, e, i64);
                vv[j] = vals[e];
            }
        }
        #pragma unroll
        for (int j = 0; j < 4; ++j) {
            int r = rloc[k0 + j];
            if (r >= 0) {
                int b = r >> RPB_SHIFT;
                int pos = base[b] + atomicAdd(&h[b], 1);
                if (pos < (b + 1) * CAP)   // overflow guard
                    recs[pos] = make_uint2(
                        ((unsigned)(r & (RPB - 1)) << 20) | (unsigned)cc[j],
                        __float_as_uint(vv[j]));
            }
        }
    }
}

// ---------------------------------------------------------------------------
// Phase 2: per-bucket counting sort (128 row bins) into row-contiguous order.
// Emits split arrays rc[pos]=col (u32), rv[pos]=val (fp16), srange[row].
// 512 threads for more in-flight work.
// ---------------------------------------------------------------------------
__global__ __launch_bounds__(512) void bsort_kernel(
    const int* __restrict__ gcur, const uint2* __restrict__ recs,
    unsigned* __restrict__ rc, ushort* __restrict__ rv,
    uint2* __restrict__ srange, int N) {
    __shared__ int cnt[RPB];
    __shared__ int scn[RPB];
    __shared__ int rbase[RPB];
    const int b = blockIdx.x;
    const int tid = threadIdx.x;
    const int s = b * CAP;
    int n = gcur[b];
    if (n > CAP) n = CAP;

    if (tid < RPB) cnt[tid] = 0;
    __syncthreads();

    for (int i = tid; i < n; i += 512)
        atomicAdd(&cnt[recs[s + i].x >> 20], 1);
    __syncthreads();

    if (tid < RPB) scn[tid] = cnt[tid];
    __syncthreads();
    for (int d = 1; d < RPB; d <<= 1) {
        int u = (tid < RPB && tid >= d) ? scn[tid - d] : 0;
        __syncthreads();
        if (tid < RPB) scn[tid] += u;
        __syncthreads();
    }
    if (tid < RPB) {
        int excl = scn[tid] - cnt[tid];
        rbase[tid] = excl;
        int row = b * RPB + tid;
        if (row < N) srange[row] = make_uint2(s + excl, s + excl + cnt[tid]);
        cnt[tid] = 0;              // reuse as cursor
    }
    __syncthreads();

    for (int i = tid; i < n; i += 512) {
        uint2 e = recs[s + i];
        int lr = e.x >> 20;
        int pos = s + rbase[lr] + atomicAdd(&cnt[lr], 1);
        rc[pos] = e.x & 0xFFFFFu;
        rv[pos] = __half_as_ushort(__float2half_rn(__uint_as_float(e.y)));
    }
}

// ---------------------------------------------------------------------------
// Phase 3 (x DBLK launches): gather one 16-dim block. 8 threads per row:
// 4 dim-lanes (4 dims = 8B/edge) x 2 edge-parity groups -> N*8 = 800K threads
// per pass (vs round-11's 200K that left the pass latency-bound). Partial
// sums combined with one __shfl_xor(4); lanes epar==0 store 64B/row (NT).
// x sub-table (3.2MB) stays L2-resident; kernel boundary = free phase barrier.
// ---------------------------------------------------------------------------
__global__ __launch_bounds__(256) void gather_dim_kernel(
    const uint2* __restrict__ srange, const unsigned* __restrict__ rc,
    const ushort* __restrict__ rv, const ushort* __restrict__ xqb,
    float* __restrict__ out, int N, int dbase) {
    int t = blockIdx.x * 256 + threadIdx.x;
    int row = t >> 3;
    if (row >= N) return;
    const int sub = t & 7;
    const int epar = sub >> 2;        // edge-parity group (0/1)
    const int dslot = sub & 3;        // 4-dim slot within the 16-dim block

    uint2 rg = srange[row];
    int e = (int)rg.x + epar;
    const int e_end = (int)rg.y;
    const ushort* xb = xqb + dslot * 4;
    f32x4 A = {};

    #define ACC4(C, V)                                                     \
        {                                                                  \
            uint2 u = *(const uint2*)(xb + (size_t)(C) * DPB);             \
            float2 f0 = __half22float2(*(const __half2*)&u.x);             \
            float2 f1 = __half22float2(*(const __half2*)&u.y);             \
            A[0] += (V) * f0.x; A[1] += (V) * f0.y;                        \
            A[2] += (V) * f1.x; A[3] += (V) * f1.y;                        \
        }

    for (; e + 6 < e_end; e += 8) {   // 4 edges of this parity in flight
        unsigned c0 = rc[e],     c1 = rc[e + 2];
        unsigned c2 = rc[e + 4], c3 = rc[e + 6];
        float v0 = h2f(rv[e]),     v1 = h2f(rv[e + 2]);
        float v2 = h2f(rv[e + 4]), v3 = h2f(rv[e + 6]);
        ACC4(c0, v0); ACC4(c1, v1); ACC4(c2, v2); ACC4(c3, v3);
    }
    for (; e < e_end; e += 2) {
        unsigned c = rc[e];
        float v = h2f(rv[e]);
        ACC4(c, v);
    }
    #undef ACC4

    // combine even/odd-edge partials: lane^4 = same row/dslot, other parity
    A[0] += __shfl_xor(A[0], 4);
    A[1] += __shfl_xor(A[1], 4);
    A[2] += __shfl_xor(A[2], 4);
    A[3] += __shfl_xor(A[3], 4);

    if (epar == 0) {
        f32x4* op = (f32x4*)(out + (size_t)row * EMBED_DIM + dbase + dslot * 4);
        __builtin_nontemporal_store(A, op);
    }
}

// ---------------------------------------------------------------------------
// Fallback: atomic COO (f32) if workspace/shape constraints violated.
// ---------------------------------------------------------------------------
__global__ __launch_bounds__(256) void spmv_coo_kernel(
    const void* __restrict__ rows_p, const void* __restrict__ cols_p,
    const float* __restrict__ vals, const float* __restrict__ x,
    float* __restrict__ out, const int* __restrict__ flag_p, int n_edges) {
    const bool i64 = (*flag_p != 0);
    const int lane16 = threadIdx.x & 15;
    long long t      = (long long)blockIdx.x * blockDim.x + threadIdx.x;
    long long stride = (long long)gridDim.x * blockDim.x;
    long long total  = (long long)n_edges * 16;
    for (; t < total; t += stride) {
        int e = (int)(t >> 4);
        int r = load_idx(rows_p, e, i64);
        int c = load_idx(cols_p, e, i64);
        float v = vals[e];
        float4 xv = ((const float4*)(x + (long long)c * EMBED_DIM))[lane16];
        float* o = out + (long long)r * EMBED_DIM + lane16 * 4;
        unsafeAtomicAdd(o + 0, xv.x * v);
        unsafeAtomicAdd(o + 1, xv.y * v);
        unsafeAtomicAdd(o + 2, xv.z * v);
        unsafeAtomicAdd(o + 3, xv.w * v);
    }
}

extern "C" void kernel_launch(void* const* d_in, const int* in_sizes, int n_in,
                              void* d_out, int out_size, void* d_ws, size_t ws_size,
                              hipStream_t stream) {
    const float* x    = (const float*)d_in[0];
    const void*  rows = d_in[1];
    const void*  cols = d_in[2];
    const float* vals = (const float*)d_in[3];
    float* out = (float*)d_out;
    const int E = in_sizes[1];
    const int N = out_size / EMBED_DIM;
    const int NB = (N + RPB - 1) >> RPB_SHIFT;

    // Workspace: flag[4 ints] | gcur[NBMAX ints] | xq[DBLK*N*DPB ushort] |
    // srange[N uint2] | recs[NB*CAP uint2] | rc[NB*CAP u32] | rv[NB*CAP u16]
    int*      base   = (int*)d_ws;
    int*      flag   = base;
    int*      gcur   = base + 4;
    ushort*   xq     = (ushort*)(base + 4 + NBMAX);
    uint2*    srange = (uint2*)(xq + (size_t)DBLK * N * DPB);
    uint2*    recs   = srange + N;
    unsigned* rc     = (unsigned*)(recs + (size_t)NB * CAP);
    ushort*   rv     = (ushort*)(rc + (size_t)NB * CAP);
    const size_t needed = (size_t)(4 + NBMAX) * 4
                        + (size_t)DBLK * N * DPB * 2
                        + (size_t)N * 8
                        + (size_t)NB * CAP * (8 + 4 + 2);

    if (ws_size < needed || NB > NBMAX || N > (1 << 20) ||
        (size_t)NB * CAP < (size_t)E / 2) {
        detect_zero_kernel<<<1, 1024, 0, stream>>>((const unsigned int*)rows,
                                                   base, 0);
        (void)hipMemsetAsync(d_out, 0, (size_t)out_size * sizeof(float), stream);
        spmv_coo_kernel<<<8192, 256, 0, stream>>>(rows, cols, vals, x, out,
                                                  flag, E);
        return;
    }

    detect_zero_kernel<<<1, 1024, 0, stream>>>((const unsigned int*)rows,
                                               base, NB);
    xconv_kernel<<<(N * 8 + 255) / 256, 256, 0, stream>>>(x, xq, N);
    const int grid_c = (E + CHUNK - 1) / CHUNK;
    bscatter_kernel<<<grid_c, SCAT_T, 0, stream>>>(rows, cols, vals, gcur,
                                                   recs, flag, E);
    bsort_kernel<<<NB, 512, 0, stream>>>(gcur, recs, rc, rv, srange, N);
    const int grid_g = (N * 8 + 255) / 256;
    for (int b = 0; b < DBLK; ++b)
        gather_dim_kernel<<<grid_g, 256, 0, stream>>>(
            srange, rc, rv, xq + (size_t)b * N * DPB, out, N, b * DPB);
}